// Round 6
// baseline (53455.640 us; speedup 1.0000x reference)
//
#include <hip/hip_runtime.h>
#include <math.h>

// Problem constants
#define B 64
#define T 512
#define F 256
#define U 1024
#define NBLK 256
#define NTH 512
#define WPAD 68   // zbuf row stride (floats): 68%32=4 -> conflict-free b128 partial stores

typedef unsigned short ushort_t;
typedef __attribute__((ext_vector_type(8))) _Float16 f16x8_t;  // MFMA A/B frag (4 VGPR)
typedef __attribute__((ext_vector_type(4))) float f32x4_t;     // MFMA C/D frag

// ---------------- workspace layout (BYTE offsets) ----------------
static const size_t OFF_HT2  = 0;                  // fp32 h2 [U][B]: 262144
static const size_t OFF_STATS= 262144;             // fp32 [2 parity][2][B]: 1024
static const size_t OFF_COND = 263168;             // int[512]: 2048
static const size_t OFF_BAR  = 265216;             // barrier region: 32768
// bar int-offsets: sub[i]=i*16 (i<16); master=256; minibar=272; gens=288+g*16
static const size_t OFF_HB   = 297984;             // f16 h [2][3][B][U]: 786432
static const size_t OFF_XB   = 1084416;            // f16 xbuf [B][F]: 32768
static const size_t OFF_PW0  = 1117184;            // f16 [256 g][40 kt][512]: 10485760
static const size_t OFF_PW1  = 11602944;           // f16 [256][64][512]: 16777216
static const size_t OFF_PW2  = 28380160;           // f16 [256][64][512]: 16777216
static const size_t ZERO_BYTES = OFF_PW0;          // state region zeroed each launch

__device__ __forceinline__ float sigm(float x) {
    return 1.0f / (1.0f + __expf(-x));
}

__device__ __forceinline__ ushort_t f2h(float x) {   // RNE fp32->fp16
    _Float16 h = (_Float16)x;
    union { _Float16 h; ushort_t u; } v; v.h = h;
    return v.u;
}

// Grid barrier with ZERO-CONTENTION exit (round-6 change).
// Round-5 lesson: 256 leaders polling ONE line serialize at the coherence
// point (~15us/barrier). Now: hierarchical arrival (16 lines x 16 adds),
// releaser broadcasts epoch to 256 per-block gen lines (64 lanes x 4 stores),
// each block polls ITS OWN line -> no same-line contention. Relaxed polls
// (no L2 inv per poll, round-4 lesson); one acquire fence at exit.
__device__ __forceinline__ void grid_barrier(int* bar, int epoch) {
    __syncthreads();
    const int tid = threadIdx.x;
    if (tid < 64) {
        const int g = blockIdx.x;
        __builtin_amdgcn_fence(__ATOMIC_RELEASE, "agent");   // flush my writes
        bool last = false;
        if (tid == 0) {
            int prev = __hip_atomic_fetch_add(bar + (g & 15) * 16, 1,
                                              __ATOMIC_RELAXED, __HIP_MEMORY_SCOPE_AGENT);
            if (prev == 15) {
                int pm = __hip_atomic_fetch_add(bar + 256, 1,
                                                __ATOMIC_RELAXED, __HIP_MEMORY_SCOPE_AGENT);
                if (pm == 15) last = true;
            }
        }
        if (__ballot(last) != 0ULL) {   // wave-uniform: this block releases
            if (tid < 16)
                __hip_atomic_store(bar + tid * 16, 0, __ATOMIC_RELAXED,
                                   __HIP_MEMORY_SCOPE_AGENT);
            if (tid == 0)
                __hip_atomic_store(bar + 256, 0, __ATOMIC_RELAXED,
                                   __HIP_MEMORY_SCOPE_AGENT);
            __builtin_amdgcn_fence(__ATOMIC_RELEASE, "agent");  // resets before gens
            #pragma unroll
            for (int i = 0; i < 4; ++i)
                __hip_atomic_store(bar + 288 + (tid * 4 + i) * 16, epoch,
                                   __ATOMIC_RELAXED, __HIP_MEMORY_SCOPE_AGENT);
        }
        if (tid == 0) {
            int* mygen = bar + 288 + g * 16;
            int spins = 0;
            while (__hip_atomic_load(mygen, __ATOMIC_RELAXED,
                                     __HIP_MEMORY_SCOPE_AGENT) < epoch) {
                __builtin_amdgcn_s_sleep(4);
                if ((++spins & 63) == 0)   // hang insurance
                    (void)__hip_atomic_load(mygen, __ATOMIC_ACQUIRE,
                                            __HIP_MEMORY_SCOPE_AGENT);
            }
        }
        __builtin_amdgcn_fence(__ATOMIC_ACQUIRE, "agent");   // the one inv
    }
    __syncthreads();
}

// Prep: decode conditioned_lst (bool-u8 vs int32 sniff), init f16 xbuf.
__global__ void prep_kernel(const unsigned char* __restrict__ condraw,
                            const float* __restrict__ input,
                            unsigned char* __restrict__ wsb) {
    __shared__ int s_not_int32;
    const int tid = threadIdx.x;
    if (tid == 0) s_not_int32 = 0;
    __syncthreads();
    if (tid < 512 && (tid & 3) != 0) {
        if (condraw[tid] != 0) s_not_int32 = 1;
    }
    __syncthreads();
    const int is32 = (s_not_int32 == 0);
    int* condw = (int*)(wsb + OFF_COND);
    if (tid < 512) {
        int cv = is32 ? ((const int*)condraw)[tid] : (int)condraw[tid];
        condw[tid] = (cv != 0) ? 1 : 0;
    }
    ushort_t* xb = (ushort_t*)(wsb + OFF_XB);
    for (int i = tid; i < B * F; i += blockDim.x) {
        const int b = i >> 8, f = i & 255;
        xb[i] = f2h(input[(size_t)b * (T * F) + f]);
    }
}

// Repack fp32 weights -> fp16 in MFMA B-fragment order:
// PW_l[((g*KT + kt)*64 + L)*8 + j] = W_l[k][col], k = kt*32 + (L>>4)*8 + j,
// n = L&15, col = (n>>2)*1024 + g*4 + (n&3)
__global__ void repack_kernel(const float* __restrict__ W0,
                              const float* __restrict__ W1,
                              const float* __restrict__ W2,
                              unsigned char* __restrict__ wsb) {
    ushort_t* P0 = (ushort_t*)(wsb + OFF_PW0);
    ushort_t* P1 = (ushort_t*)(wsb + OFF_PW1);
    ushort_t* P2 = (ushort_t*)(wsb + OFF_PW2);
    const size_t stride = (size_t)gridDim.x * blockDim.x;
    const size_t tid = (size_t)blockIdx.x * blockDim.x + threadIdx.x;
    const size_t N0 = (size_t)256 * 40 * 512;
    const size_t N12 = (size_t)256 * 64 * 512;
    for (size_t i = tid; i < N0; i += stride) {
        const int g = (int)(i / 20480);
        const int r = (int)(i % 20480);
        const int kt = r >> 9, s = r & 511, L = s >> 3, j = s & 7;
        const int k = kt * 32 + ((L >> 4) << 3) + j;
        const int n = L & 15;
        const int col = ((n >> 2) << 10) + (g << 2) + (n & 3);
        P0[i] = f2h(W0[(size_t)k * 4096 + col]);
    }
    for (size_t i = tid; i < N12; i += stride) {
        const int g = (int)(i / 32768);
        const int r = (int)(i % 32768);
        const int kt = r >> 9, s = r & 511, L = s >> 3, j = s & 7;
        const int k = kt * 32 + ((L >> 4) << 3) + j;
        const int n = L & 15;
        const int col = ((n >> 2) << 10) + (g << 2) + (n & 3);
        const size_t src = (size_t)k * 4096 + col;
        P1[i] = f2h(W1[src]);
        P2[i] = f2h(W2[src]);
    }
}

// One layer's MFMA work for one wave: KTW ktiles in chunks of 4; all 20
// chunk loads (4 B + 16 A frags) issued before any MFMA.
template<int KTW>
__device__ __forceinline__ void layer_mfma(const ushort_t* __restrict__ pwb,
                                           int kt0,
                                           const ushort_t* __restrict__ xsrc,
                                           const ushort_t* __restrict__ hsrc,
                                           int K1, int S1,
                                           int lane, int ln15, int kofs,
                                           f32x4_t acc[4]) {
    #pragma unroll
    for (int base = 0; base < KTW; base += 4) {
        const int CH = (KTW - base) < 4 ? (KTW - base) : 4;
        f16x8_t Bb[4];
        f16x8_t Ab[4][4];
        #pragma unroll
        for (int c = 0; c < 4; ++c) {
            if (c < CH) {
                const int kt = kt0 + base + c;
                Bb[c] = *(const f16x8_t*)(pwb + (size_t)kt * 512 + lane * 8);
                const int kg = kt * 32;
                const ushort_t* ab;
                int rs;
                if (kg < K1) { ab = xsrc + kg; rs = S1; }
                else         { ab = hsrc + (kg - K1); rs = U; }
                const ushort_t* lp = ab + (size_t)ln15 * rs + kofs;
                #pragma unroll
                for (int mt = 0; mt < 4; ++mt)
                    Ab[c][mt] = *(const f16x8_t*)(lp + (size_t)mt * 16 * rs);
            }
        }
        #pragma unroll
        for (int c = 0; c < 4; ++c) {
            if (c < CH) {
                #pragma unroll
                for (int mt = 0; mt < 4; ++mt)
                    acc[mt] = __builtin_amdgcn_mfma_f32_16x16x32_f16(
                        Ab[c][mt], Bb[c], acc[mt], 0, 0, 0);
            }
        }
    }
}

__global__ void __launch_bounds__(NTH, 2)
lstm_persistent(const float* __restrict__ input,
                const float* __restrict__ b0, const float* __restrict__ b1,
                const float* __restrict__ b2,
                const float* __restrict__ Wd, const float* __restrict__ bd,
                const float* __restrict__ gamma, const float* __restrict__ beta,
                float* __restrict__ out, unsigned char* __restrict__ wsb) {
    const int g = blockIdx.x;
    const int tid = threadIdx.x;
    const int lane = tid & 63;
    const int wv = __builtin_amdgcn_readfirstlane(tid >> 6);  // 0..7
    const int ln15 = lane & 15;
    const int quad = lane >> 4;
    const int kofs = quad << 3;

    float* hT2 = (float*)(wsb + OFF_HT2);          // fp32 [U][B]
    float* stats = (float*)(wsb + OFF_STATS);
    const int* cond = (const int*)(wsb + OFF_COND);
    int* bar = (int*)(wsb + OFF_BAR);
    ushort_t* hb = (ushort_t*)(wsb + OFF_HB);      // f16 [2][3][B][U]
    ushort_t* xb = (ushort_t*)(wsb + OFF_XB);      // f16 [B][F]
    const ushort_t* PWa[3] = {(const ushort_t*)(wsb + OFF_PW0),
                              (const ushort_t*)(wsb + OFF_PW1),
                              (const ushort_t*)(wsb + OFF_PW2)};

    __shared__ float zbuf[128 * WPAD];   // 34.8 KB

    const int u0 = g << 2;   // block's unit quad
    const int f0 = g << 2;   // dense cols (g < 64)

    const int eb = tid & 63;
    const int eu = (tid >> 6) & 3;
    float creg[3] = {0.f, 0.f, 0.f};   // fp32 cell state (valid for tid<256)

    int epoch = 0;
    for (int t = 0; t < T; ++t) {
        const int p = t & 1;
        const int pn = p ^ 1;

        // ---------------- LSTM layers: MFMA z^(l) = X W ----------------
        for (int l = 0; l < 3; ++l) {
            const int K1 = (l == 0) ? F : U;
            const int S1 = (l == 0) ? F : U;
            const ushort_t* xsrc = (l == 0) ? xb
                                 : (hb + ((size_t)(pn * 3 + (l - 1))) * B * U);
            const ushort_t* hsrc = hb + ((size_t)(p * 3 + l)) * B * U;
            const ushort_t* pwb = PWa[l] + (size_t)g * ((l == 0) ? 40 : 64) * 512;

            f32x4_t acc[4];
            #pragma unroll
            for (int mt = 0; mt < 4; ++mt) acc[mt] = (f32x4_t){0.f, 0.f, 0.f, 0.f};

            if (l == 0) layer_mfma<5>(pwb, wv * 5, xsrc, hsrc, K1, S1,
                                      lane, ln15, kofs, acc);
            else        layer_mfma<8>(pwb, wv * 8, xsrc, hsrc, K1, S1,
                                      lane, ln15, kofs, acc);

            __syncthreads();
            {
                float* zrow = zbuf + (size_t)(wv * 16 + ln15) * WPAD;
                #pragma unroll
                for (int mt = 0; mt < 4; ++mt)
                    *(f32x4_t*)(zrow + mt * 16 + (quad << 2)) = acc[mt];
            }
            __syncthreads();

            if (tid < 256) {   // gate epilogue: (b=eb, unit u0+eu)
                const float* bvec = (l == 0) ? b0 : ((l == 1) ? b1 : b2);
                float z[4];
                #pragma unroll
                for (int q = 0; q < 4; ++q) {
                    float s = bvec[(q << 10) + u0 + eu];
                    #pragma unroll
                    for (int w = 0; w < 8; ++w)
                        s += zbuf[(size_t)(w * 16 + q * 4 + eu) * WPAD + eb];
                    z[q] = s;
                }
                const float ig = sigm(z[0]);
                const float gg = tanhf(z[1]);
                const float fg = sigm(z[2] + 1.0f);   // forget_bias = 1.0
                const float og = sigm(z[3]);
                const float cn = creg[l] * fg + ig * gg;
                const float hn = og * tanhf(cn);
                creg[l] = cn;
                hb[((size_t)(pn * 3 + l)) * B * U + (size_t)eb * U + u0 + eu] = f2h(hn);
                if (l == 2) hT2[(size_t)(u0 + eu) * B + eb] = hn;
            }
            grid_barrier(bar, ++epoch);
        }

        // ------- dense + LN stats + mini-barrier + LN + emit (ONE phase) -------
        if (g < 64) {
            float accd[4] = {0.f, 0.f, 0.f, 0.f};
            const int k0 = wv << 7;   // U/8 = 128 per wave
            for (int base = 0; base < 128; base += 16) {
                float xv[16]; float4 w4[16];
                #pragma unroll
                for (int c = 0; c < 16; ++c) {   // 32 loads in flight
                    const int k = k0 + base + c;
                    xv[c] = hT2[(size_t)k * B + lane];
                    w4[c] = *(const float4*)(Wd + (size_t)k * F + f0);
                }
                #pragma unroll
                for (int c = 0; c < 16; ++c) {
                    accd[0] = fmaf(w4[c].x, xv[c], accd[0]);
                    accd[1] = fmaf(w4[c].y, xv[c], accd[1]);
                    accd[2] = fmaf(w4[c].z, xv[c], accd[2]);
                    accd[3] = fmaf(w4[c].w, xv[c], accd[3]);
                }
            }
            __syncthreads();
            #pragma unroll
            for (int jj = 0; jj < 4; ++jj)
                zbuf[(size_t)(wv * 16 + jj) * WPAD + lane] = accd[jj];
            __syncthreads();
            if (wv == 0) {
                const float4 bd4 = *(const float4*)(bd + f0);
                float yv[4];
                float s = 0.f, ss = 0.f;
                #pragma unroll
                for (int jj = 0; jj < 4; ++jj) {
                    float y = 0.f;
                    #pragma unroll
                    for (int w = 0; w < 8; ++w)
                        y += zbuf[(size_t)(w * 16 + jj) * WPAD + lane];
                    y += (jj == 0) ? bd4.x : (jj == 1) ? bd4.y : (jj == 2) ? bd4.z : bd4.w;
                    yv[jj] = y;
                    s += y;
                    ss += y * y;
                }
                float* st = stats + (size_t)(t & 1) * 2 * B;
                atomicAdd(&st[lane], s);
                atomicAdd(&st[B + lane], ss);
                // ---- mini-barrier: 64 dense blocks, monotonic counter ----
                __builtin_amdgcn_fence(__ATOMIC_RELEASE, "agent");
                if (lane == 0) {
                    __hip_atomic_fetch_add(bar + 272, 1, __ATOMIC_RELAXED,
                                           __HIP_MEMORY_SCOPE_AGENT);
                    const int target = (t + 1) * 64;
                    int spins = 0;
                    while (__hip_atomic_load(bar + 272, __ATOMIC_RELAXED,
                                             __HIP_MEMORY_SCOPE_AGENT) < target) {
                        __builtin_amdgcn_s_sleep(4);
                        if ((++spins & 63) == 0)
                            (void)__hip_atomic_load(bar + 272, __ATOMIC_ACQUIRE,
                                                    __HIP_MEMORY_SCOPE_AGENT);
                    }
                }
                __builtin_amdgcn_fence(__ATOMIC_ACQUIRE, "agent");
                // ---- LN + ReLU emit ----
                const float mu = st[lane] * (1.0f / F);
                const float var = st[B + lane] * (1.0f / F) - mu * mu;
                const float rs = rsqrtf(var + 1e-12f);
                const float4 gm = *(const float4*)(gamma + f0);
                const float4 bt = *(const float4*)(beta + f0);
                float em[4];
                em[0] = fmaxf((yv[0] - mu) * rs * gm.x + bt.x, 0.0f);
                em[1] = fmaxf((yv[1] - mu) * rs * gm.y + bt.y, 0.0f);
                em[2] = fmaxf((yv[2] - mu) * rs * gm.z + bt.z, 0.0f);
                em[3] = fmaxf((yv[3] - mu) * rs * gm.w + bt.w, 0.0f);
                *(float4*)(out + (size_t)lane * (T * F) + (size_t)t * F + f0) =
                    make_float4(em[0], em[1], em[2], em[3]);
                if (t + 1 < T) {
                    float xn[4];
                    if (cond[t + 1] != 0) {
                        const float4 iv = *(const float4*)(input + (size_t)lane * (T * F) +
                                                           (size_t)(t + 1) * F + f0);
                        xn[0] = iv.x; xn[1] = iv.y; xn[2] = iv.z; xn[3] = iv.w;
                    } else {
                        xn[0] = em[0]; xn[1] = em[1]; xn[2] = em[2]; xn[3] = em[3];
                    }
                    #pragma unroll
                    for (int jj = 0; jj < 4; ++jj)
                        xb[(size_t)lane * F + f0 + jj] = f2h(xn[jj]);
                }
            }
        } else if (g == 64 && wv == 0) {
            // zero other-parity stats for step t+1 (flushed by bar4 release)
            float* st2 = stats + (size_t)((t + 1) & 1) * 2 * B;
            st2[lane] = 0.0f;
            st2[B + lane] = 0.0f;
        }
        grid_barrier(bar, ++epoch);
    }
}

extern "C" void kernel_launch(void* const* d_in, const int* in_sizes, int n_in,
                              void* d_out, int out_size, void* d_ws, size_t ws_size,
                              hipStream_t stream) {
    const float* input = (const float*)d_in[0];
    const unsigned char* condraw = (const unsigned char*)d_in[1];
    const float* W0 = (const float*)d_in[2];
    const float* b0 = (const float*)d_in[3];
    const float* W1 = (const float*)d_in[4];
    const float* b1 = (const float*)d_in[5];
    const float* W2 = (const float*)d_in[6];
    const float* b2 = (const float*)d_in[7];
    const float* Wd = (const float*)d_in[8];
    const float* bd = (const float*)d_in[9];
    const float* gamma = (const float*)d_in[10];
    const float* beta = (const float*)d_in[11];
    float* out = (float*)d_out;
    unsigned char* wsb = (unsigned char*)d_ws;

    hipMemsetAsync(d_ws, 0, ZERO_BYTES, stream);
    prep_kernel<<<1, 512, 0, stream>>>(condraw, input, wsb);
    repack_kernel<<<2048, 256, 0, stream>>>(W0, W1, W2, wsb);
    lstm_persistent<<<NBLK, NTH, 0, stream>>>(input, b0, b1, b2, Wd, bd,
                                              gamma, beta, out, wsb);
}